// Round 2
// baseline (682.621 us; speedup 1.0000x reference)
//
#include <hip/hip_runtime.h>
#include <hip/hip_bf16.h>
#include <math.h>

// ---------------- ws layout (float offsets) ----------------
// wq0:0(320) bq0:320(64) wq1:384(4096) bq1:4480(64) wq2:4544(4096) bq2:8640(64)
// wq3:8704(4096) bq3:12800(64) wq4:12864(64) bq4:12928(1)
// gt0:12932(128*4) gt1:13444(512*4) gt2:15492(2048*4)  end=23684 floats (94.7 KB)
#define WQ0 0
#define BQ0 320
#define WQ1 384
#define BQ1 4480
#define WQ2 4544
#define BQ2 8640
#define WQ3 8704
#define BQ3 12800
#define WQ4 12864
#define BQ4 12928
#define GT0 12932
#define GT1 13444
#define GT2 15492

__device__ void block_minmax(float mn, float mx, float* omn, float* omx) {
    __shared__ float smn[4], smx[4];
    __syncthreads();  // protect smn/smx reuse across calls
    #pragma unroll
    for (int off = 32; off > 0; off >>= 1) {
        mn = fminf(mn, __shfl_down(mn, off));
        mx = fmaxf(mx, __shfl_down(mx, off));
    }
    int wid = threadIdx.x >> 6, lane = threadIdx.x & 63;
    if (lane == 0) { smn[wid] = mn; smx[wid] = mx; }
    __syncthreads();
    if (threadIdx.x == 0) {
        float a = smn[0], b = smx[0];
        for (int i = 1; i < 4; ++i) { a = fminf(a, smn[i]); b = fmaxf(b, smx[i]); }
        smn[0] = a; smx[0] = b;
    }
    __syncthreads();
    *omn = smn[0]; *omx = smx[0];
}

// _qround forward: round((x-mn)/scale)*scale + mn, scale = max(mx-mn,1e-8)/63
// jnp.round = round-half-even -> rintf. All ops f32, same sequence as ref.
__device__ void quantize_tensor(const float* __restrict__ src, int n, float* __restrict__ dst) {
    float mn = 3.4e38f, mx = -3.4e38f;
    for (int i = threadIdx.x; i < n; i += blockDim.x) {
        float v = src[i];
        mn = fminf(mn, v); mx = fmaxf(mx, v);
    }
    float gmn, gmx;
    block_minmax(mn, mx, &gmn, &gmx);
    float scale = fmaxf(gmx - gmn, 1e-8f) / 63.0f;
    for (int i = threadIdx.x; i < n; i += blockDim.x) {
        float v = src[i];
        dst[i] = rintf((v - gmn) / scale) * scale + gmn;
    }
}

// Prep: block 0 quantizes weights; blocks 1..11 build grid tables (forward of
// _grid's STE = codebook[argmax(indices, axis=1)], one thread per grid row).
__global__ void vinr_prep(
    const float* __restrict__ cb0, const float* __restrict__ ind0,
    const float* __restrict__ cb1, const float* __restrict__ ind1,
    const float* __restrict__ cb2, const float* __restrict__ ind2,
    const float* __restrict__ w0, const float* __restrict__ b0,
    const float* __restrict__ w1, const float* __restrict__ b1,
    const float* __restrict__ w2, const float* __restrict__ b2,
    const float* __restrict__ w3, const float* __restrict__ b3,
    const float* __restrict__ w4, const float* __restrict__ b4,
    float* __restrict__ ws)
{
    if (blockIdx.x == 0) {
        quantize_tensor(w0, 320, ws + WQ0);
        quantize_tensor(b0, 64, ws + BQ0);
        quantize_tensor(w1, 4096, ws + WQ1);
        quantize_tensor(b1, 64, ws + BQ1);
        quantize_tensor(w2, 4096, ws + WQ2);
        quantize_tensor(b2, 64, ws + BQ2);
        quantize_tensor(w3, 4096, ws + WQ3);
        quantize_tensor(b3, 64, ws + BQ3);
        quantize_tensor(w4, 64, ws + WQ4);
        quantize_tensor(b4, 1, ws + BQ4);
    } else {
        int r = (int)(blockIdx.x - 1) * (int)blockDim.x + (int)threadIdx.x;
        const float* ind; const float* cb; float* dst;
        if (r < 128)       { ind = ind0 + r * 64;          cb = cb0; dst = ws + GT0 + r * 4; }
        else if (r < 640)  { int rr = r - 128;  ind = ind1 + rr * 64; cb = cb1; dst = ws + GT1 + rr * 4; }
        else if (r < 2688) { int rr = r - 640;  ind = ind2 + rr * 64; cb = cb2; dst = ws + GT2 + rr * 4; }
        else return;
        // first-occurrence argmax (matches jnp.argmax tie-breaking)
        float best = -3.4e38f; int bi = 0;
        for (int j = 0; j < 64; ++j) {
            float v = ind[j];
            if (v > best) { best = v; bi = j; }
        }
        #pragma unroll
        for (int d = 0; d < 4; ++d) dst[d] = cb[bi * 4 + d];
    }
}

__device__ inline float gelu_exact(float v) {
    return 0.5f * v * (1.0f + erff(v * 0.7071067811865476f));
}

__global__ __launch_bounds__(256) void vinr_main(
    const float* __restrict__ x, const float* __restrict__ ws,
    float* __restrict__ out, int N)
{
    int i = (int)blockIdx.x * 256 + (int)threadIdx.x;
    if (i >= N) return;
    // x row: [feat, coord]; one 8B load
    float2 xr = ((const float2*)x)[i];
    float feat  = xr.x;
    float coord = xr.y;

    float g0 = 0.f, g1 = 0.f, g2 = 0.f, g3 = 0.f;
    const int RES[3]  = {128, 512, 2048};
    const int GOFF[3] = {GT0, GT1, GT2};
    #pragma unroll
    for (int gi = 0; gi < 3; ++gi) {
        int res = RES[gi];
        float c = (coord + 1.0f) * 0.5f * (float)(res - 1);
        int left  = min((int)floorf(c), res - 2);
        int right = max((int)ceilf(c), 1);
        float w = c - (float)left;
        const float4* gt = (const float4*)(ws + GOFF[gi]);
        float4 gl = gt[left];
        float4 gr = gt[right];
        float wm = 1.0f - w;
        g0 += wm * gl.x + w * gr.x;
        g1 += wm * gl.y + w * gr.y;
        g2 += wm * gl.z + w * gr.z;
        g3 += wm * gl.w + w * gr.w;
    }

    // layer 0: 5 -> 64 (weights uniform across lanes -> scalar/broadcast loads)
    float h[64];
    {
        const float* w0 = ws + WQ0;
        const float* b0 = ws + BQ0;
        #pragma unroll
        for (int j = 0; j < 64; ++j) {
            float a = b0[j];
            a = fmaf(g0,   w0[j],       a);
            a = fmaf(g1,   w0[64 + j],  a);
            a = fmaf(g2,   w0[128 + j], a);
            a = fmaf(g3,   w0[192 + j], a);
            a = fmaf(feat, w0[256 + j], a);
            h[j] = a;
        }
    }

    // layers 1..3: gelu + 64x64
    const int WOFF[3] = {WQ1, WQ2, WQ3};
    #pragma unroll 1
    for (int l = 0; l < 3; ++l) {
        const float* wl = ws + WOFF[l];
        const float* bl = wl + 4096;
        float a[64];
        #pragma unroll
        for (int k = 0; k < 64; ++k) a[k] = gelu_exact(h[k]);
        #pragma unroll
        for (int j = 0; j < 64; ++j) h[j] = bl[j];
        #pragma unroll
        for (int k = 0; k < 64; ++k) {
            float ak = a[k];
            const float* wr = wl + k * 64;
            #pragma unroll
            for (int j = 0; j < 64; ++j) h[j] = fmaf(ak, wr[j], h[j]);
        }
    }

    // layer 4: gelu + 64 -> 1, then tanh
    {
        const float* w4 = ws + WQ4;
        float acc = ws[BQ4];
        #pragma unroll
        for (int k = 0; k < 64; ++k) acc = fmaf(gelu_exact(h[k]), w4[k], acc);
        out[i] = tanhf(acc);
    }
}

extern "C" void kernel_launch(void* const* d_in, const int* in_sizes, int n_in,
                              void* d_out, int out_size, void* d_ws, size_t ws_size,
                              hipStream_t stream) {
    const float* x    = (const float*)d_in[0];
    const float* cb0  = (const float*)d_in[1];
    const float* ind0 = (const float*)d_in[2];
    const float* cb1  = (const float*)d_in[3];
    const float* ind1 = (const float*)d_in[4];
    const float* cb2  = (const float*)d_in[5];
    const float* ind2 = (const float*)d_in[6];
    const float* w0 = (const float*)d_in[7],  * b0 = (const float*)d_in[8];
    const float* w1 = (const float*)d_in[9],  * b1 = (const float*)d_in[10];
    const float* w2 = (const float*)d_in[11], * b2 = (const float*)d_in[12];
    const float* w3 = (const float*)d_in[13], * b3 = (const float*)d_in[14];
    const float* w4 = (const float*)d_in[15], * b4 = (const float*)d_in[16];
    float* ws  = (float*)d_ws;
    float* out = (float*)d_out;

    int N = in_sizes[0] / 2;  // 1<<20

    vinr_prep<<<12, 256, 0, stream>>>(cb0, ind0, cb1, ind1, cb2, ind2,
                                      w0, b0, w1, b1, w2, b2, w3, b3, w4, b4, ws);
    int blocks = (N + 255) / 256;
    vinr_main<<<blocks, 256, 0, stream>>>(x, ws, out, N);
}